// Round 6
// baseline (400.983 us; speedup 1.0000x reference)
//
#include <hip/hip_runtime.h>
#include <hip/hip_bf16.h>
#include <math.h>

#define PAST 8191
#define SCALEF 0.0625f  // 256^-0.5
#define NB 256u

using bf = __hip_bfloat16;

__device__ __forceinline__ float bf2f(unsigned short u) {
    return __uint_as_float(((unsigned)u) << 16);
}
__device__ __forceinline__ void unpack8(uint4 r, float* f) {
    f[0] = __uint_as_float(r.x << 16);
    f[1] = __uint_as_float(r.x & 0xffff0000u);
    f[2] = __uint_as_float(r.y << 16);
    f[3] = __uint_as_float(r.y & 0xffff0000u);
    f[4] = __uint_as_float(r.z << 16);
    f[5] = __uint_as_float(r.z & 0xffff0000u);
    f[6] = __uint_as_float(r.w << 16);
    f[7] = __uint_as_float(r.w & 0xffff0000u);
}

template<bool BF16>
__device__ __forceinline__ void load8(const void* W, size_t off, float* f) {
    if constexpr (BF16) {
        uint4 r = *reinterpret_cast<const uint4*>((const unsigned short*)W + off);
        unpack8(r, f);
    } else {
        const float* p = (const float*)W + off;
        float4 a = *reinterpret_cast<const float4*>(p);
        float4 b = *reinterpret_cast<const float4*>(p + 4);
        f[0]=a.x; f[1]=a.y; f[2]=a.z; f[3]=a.w;
        f[4]=b.x; f[5]=b.y; f[6]=b.z; f[7]=b.w;
    }
}
template<bool BF16>
__device__ __forceinline__ void load4(const void* P, size_t off, float* f) {
    if constexpr (BF16) {
        uint2 r = *reinterpret_cast<const uint2*>((const unsigned short*)P + off);
        f[0] = __uint_as_float(r.x << 16); f[1] = __uint_as_float(r.x & 0xffff0000u);
        f[2] = __uint_as_float(r.y << 16); f[3] = __uint_as_float(r.y & 0xffff0000u);
    } else {
        float4 a = *reinterpret_cast<const float4*>((const float*)P + off);
        f[0]=a.x; f[1]=a.y; f[2]=a.z; f[3]=a.w;
    }
}
template<bool BF16>
__device__ __forceinline__ float load1(const void* P, int i) {
    if constexpr (BF16) return bf2f(((const unsigned short*)P)[i]);
    else return ((const float*)P)[i];
}

// ---- grid barrier: monotonic counter, agent-scope acquire spin ----
// Safe: all 256 blocks co-resident (launch_bounds(256,2), 24.7KB LDS -> >=2
// blocks/CU capacity on 256 CUs). Plain/volatile loads could see a stale
// per-XCD L2 line; __hip_atomic_load(AGENT) is coherent.
__device__ __forceinline__ void gbar(unsigned* cnt, unsigned target) {
    __syncthreads();
    if (threadIdx.x == 0) {
        __threadfence();
        atomicAdd(cnt, 1u);
        while (__hip_atomic_load(cnt, __ATOMIC_ACQUIRE, __HIP_MEMORY_SCOPE_AGENT) < target)
            __builtin_amdgcn_s_sleep(2);
        __threadfence();
    }
    __syncthreads();
}

// ---- GEMV cores: 8-deep independent load batches (round-2 proven) ----
template<bool BF16>
__device__ __forceinline__ void gemv_rows8(const void* __restrict__ W, int ldw,
                                           const float* __restrict__ xs_wave,
                                           int row0, int j, float acc[8]) {
    float f[8][8];
    #pragma unroll
    for (int r = 0; r < 8; ++r)
        load8<BF16>(W, (size_t)(row0 + r) * ldw + j, f[r]);
    #pragma unroll
    for (int r = 0; r < 8; ++r) {
        float xv = xs_wave[r];
        #pragma unroll
        for (int q = 0; q < 8; ++q) acc[q] = fmaf(xv, f[r][q], acc[q]);
    }
}
template<bool BF16>
__device__ __forceinline__ void gemv_rows16(const void* __restrict__ W, int ldw,
                                            const float* __restrict__ xs_wave,
                                            int row0, int j, float acc[8]) {
    #pragma unroll
    for (int i = 0; i < 16; i += 8) {
        float f[8][8];
        #pragma unroll
        for (int r = 0; r < 8; ++r)
            load8<BF16>(W, (size_t)(row0 + i + r) * ldw + j, f[r]);
        #pragma unroll
        for (int r = 0; r < 8; ++r) {
            float xv = xs_wave[i + r];
            #pragma unroll
            for (int q = 0; q < 8; ++q) acc[q] = fmaf(xv, f[r][q], acc[q]);
        }
    }
}

__device__ __forceinline__ void block_reduce_512(float acc[8], float* red,
                                                 int wave, int lane) {
    if (wave > 0) {
        float* dst = red + (wave - 1) * 512 + lane * 8;
        #pragma unroll
        for (int q = 0; q < 8; ++q) dst[q] = acc[q];
    }
    __syncthreads();
    if (wave == 0) {
        int o = lane * 8;
        #pragma unroll
        for (int q = 0; q < 8; ++q)
            acc[q] += red[o + q] + red[512 + o + q] + red[1024 + o + q];
    }
}

// ws layout (floats):
//   qkv   2x2560 : 0..5120        (stripes)
//   x2    2x1536 : 5120..8192
//   gacc  2x6144 : 8192..20480
//   uacc  2x6144 : 20480..32768
//   yacc  4x1536 : 32768..38912
//   attnS 16x2048: 38912..71680
//   lpart 512    : 71680..72192
// barrier counter at float idx 100000 (host-memset, outside zeroed region)

template<bool BF16>
__device__ void mega_body(const void* __restrict__ x, const void* __restrict__ kp,
                          const void* __restrict__ vp,
                          const void* __restrict__ Wq, const void* __restrict__ bq,
                          const void* __restrict__ Wk, const void* __restrict__ bk,
                          const void* __restrict__ Wv, const void* __restrict__ bv,
                          const void* __restrict__ Wo, const void* __restrict__ bo,
                          const void* __restrict__ Wg, const void* __restrict__ bg,
                          const void* __restrict__ Wu, const void* __restrict__ bu,
                          const void* __restrict__ Wd, const void* __restrict__ bd,
                          void* __restrict__ out, float* __restrict__ ws,
                          unsigned* __restrict__ bar,
                          float* xs, float* red, float* wsum) {
    const int bid = blockIdx.x;
    const int tid = threadIdx.x, wave = tid >> 6, lane = tid & 63;

    float* qkvA  = ws;
    float* x2A   = ws + 5120;
    float* gaccA = ws + 8192;
    float* uaccA = ws + 20480;
    float* yacc  = ws + 32768;
    float* attnS = ws + 38912;
    float* lpart = ws + 71680;

    // ================= phase 1: QKV (240 vblocks: 5 jb x 48 ib, 32 rows) ====
    if (bid < 240) {
        int jb = bid / 48, ib = bid % 48;
        int i0 = ib * 32;
        if (tid < 32) xs[tid] = load1<BF16>(x, i0 + tid);
        __syncthreads();
        int j = jb * 512 + lane * 8;
        const void* W; const void* bias; int ldw, jl;
        if (j < 2048)      { W = Wq; bias = bq; ldw = 2048; jl = j; }
        else if (j < 2304) { W = Wk; bias = bk; ldw = 256;  jl = j - 2048; }
        else               { W = Wv; bias = bv; ldw = 256;  jl = j - 2304; }
        float acc[8] = {0,0,0,0,0,0,0,0};
        gemv_rows8<BF16>(W, ldw, xs + wave * 8, i0 + wave * 8, jl, acc);
        block_reduce_512(acc, red, wave, lane);
        if (wave == 0) {
            if (ib == 0) {
                #pragma unroll
                for (int q = 0; q < 8; ++q) acc[q] += load1<BF16>(bias, jl + q);
            }
            float* o = qkvA + (ib & 1) * 2560;
            #pragma unroll
            for (int q = 0; q < 8; ++q) atomicAdd(&o[j + q], acc[q]);
        }
    }
    gbar(bar, 2 * NB);

    // ================= phase 2: attention (256 blocks x 32 pos, 8/wave) ====
    {
        if (tid < 8) wsum[tid] = 0.f;
        __syncthreads();
        int d0 = lane * 4;
        const float* q1 = qkvA + 2560;
        float4 qreg[8];
        #pragma unroll
        for (int h = 0; h < 8; ++h) {
            float4 a = *reinterpret_cast<const float4*>(qkvA + h * 256 + d0);
            float4 b = *reinterpret_cast<const float4*>(q1 + h * 256 + d0);
            qreg[h].x = a.x + b.x; qreg[h].y = a.y + b.y;
            qreg[h].z = a.z + b.z; qreg[h].w = a.w + b.w;
        }
        float4 ka = *reinterpret_cast<const float4*>(qkvA + 2048 + d0);
        float4 kb = *reinterpret_cast<const float4*>(q1 + 2048 + d0);
        float4 va = *reinterpret_cast<const float4*>(qkvA + 2304 + d0);
        float4 vb2 = *reinterpret_cast<const float4*>(q1 + 2304 + d0);
        float knew[4] = {ka.x+kb.x, ka.y+kb.y, ka.z+kb.z, ka.w+kb.w};
        float vnew[4] = {va.x+vb2.x, va.y+vb2.y, va.z+vb2.z, va.w+vb2.w};

        int p0 = bid * 32 + wave * 8;
        float kf[8][4], vf[8][4];
        if (p0 + 7 < PAST) {
            #pragma unroll
            for (int r = 0; r < 8; ++r)
                load4<BF16>(kp, (size_t)(p0 + r) * 256 + d0, kf[r]);
            #pragma unroll
            for (int r = 0; r < 8; ++r)
                load4<BF16>(vp, (size_t)(p0 + r) * 256 + d0, vf[r]);
        } else {
            #pragma unroll
            for (int r = 0; r < 8; ++r) {
                int p = p0 + r;
                if (p < PAST) {
                    load4<BF16>(kp, (size_t)p * 256 + d0, kf[r]);
                    load4<BF16>(vp, (size_t)p * 256 + d0, vf[r]);
                } else {
                    kf[r][0]=knew[0]; kf[r][1]=knew[1]; kf[r][2]=knew[2]; kf[r][3]=knew[3];
                    vf[r][0]=vnew[0]; vf[r][1]=vnew[1]; vf[r][2]=vnew[2]; vf[r][3]=vnew[3];
                }
            }
        }
        float part[8][8];
        #pragma unroll
        for (int r = 0; r < 8; ++r)
            #pragma unroll
            for (int h = 0; h < 8; ++h)
                part[r][h] = qreg[h].x*kf[r][0] + qreg[h].y*kf[r][1]
                           + qreg[h].z*kf[r][2] + qreg[h].w*kf[r][3];
        #pragma unroll
        for (int m = 1; m < 64; m <<= 1) {
            #pragma unroll
            for (int r = 0; r < 8; ++r)
                #pragma unroll
                for (int h = 0; h < 8; ++h)
                    part[r][h] += __shfl_xor(part[r][h], m, 64);
        }
        float o[8][4];
        #pragma unroll
        for (int h = 0; h < 8; ++h)
            #pragma unroll
            for (int r = 0; r < 4; ++r) o[h][r] = 0.f;
        float wl[8] = {0,0,0,0,0,0,0,0};
        #pragma unroll
        for (int r = 0; r < 8; ++r)
            #pragma unroll
            for (int h = 0; h < 8; ++h) {
                float w = expf(part[r][h] * SCALEF);
                wl[h] += w;
                #pragma unroll
                for (int rr = 0; rr < 4; ++rr) o[h][rr] = fmaf(w, vf[r][rr], o[h][rr]);
            }
        if (lane == 0) {
            #pragma unroll
            for (int h = 0; h < 8; ++h) atomicAdd(&wsum[h], wl[h]);
        }
        if (wave > 0) {
            float* dst = red + (wave - 1) * 2048;
            #pragma unroll
            for (int h = 0; h < 8; ++h)
                #pragma unroll
                for (int r = 0; r < 4; ++r) dst[h * 256 + d0 + r] = o[h][r];
        }
        __syncthreads();
        if (wave == 0) {
            float* os = attnS + (size_t)(bid & 15) * 2048;
            #pragma unroll
            for (int h = 0; h < 8; ++h)
                #pragma unroll
                for (int r = 0; r < 4; ++r) {
                    float v = o[h][r] + red[h*256 + d0 + r] + red[2048 + h*256 + d0 + r]
                            + red[4096 + h*256 + d0 + r];
                    atomicAdd(&os[h * 256 + d0 + r], v);
                }
        }
        if (tid < 8) atomicAdd(&lpart[tid * 64 + (bid & 63)], wsum[tid]);
    }
    gbar(bar, 3 * NB);

    // ================= phase 3: O proj + residual (96 vblocks: 3 jb x 32 ib, 64 rows)
    if (bid < 96) {
        int jb = bid / 32, ib = bid % 32;
        int i0 = ib * 64;
        int h = i0 >> 8;            // constant per vblock (64 | 256)
        if (tid < 64) {
            float v = lpart[h * 64 + tid];
            #pragma unroll
            for (int m = 1; m < 64; m <<= 1) v += __shfl_xor(v, m, 64);
            int i = i0 + tid;
            float s = 0.f;
            #pragma unroll
            for (int st = 0; st < 16; ++st) s += attnS[(size_t)st * 2048 + i];
            xs[tid] = s * (1.0f / v);
        }
        __syncthreads();
        int j = jb * 512 + lane * 8;
        float acc[8] = {0,0,0,0,0,0,0,0};
        gemv_rows16<BF16>(Wo, 1536, xs + wave * 16, i0 + wave * 16, j, acc);
        block_reduce_512(acc, red, wave, lane);
        if (wave == 0) {
            if (ib == 0) {
                #pragma unroll
                for (int q = 0; q < 8; ++q)
                    acc[q] += load1<BF16>(bo, j + q) + load1<BF16>(x, j + q);
            }
            float* o = x2A + (ib & 1) * 1536;
            #pragma unroll
            for (int q = 0; q < 8; ++q) atomicAdd(&o[j + q], acc[q]);
        }
    }
    gbar(bar, 4 * NB);

    // ================= phase 4: gate/up (576 vblocks: 2 z x 12 jb x 24 ib, 64 rows)
    for (int vb = bid; vb < 576; vb += 256) {
        int z = vb / 288, r2 = vb % 288, jb = r2 % 12, ib = r2 / 12;
        int i0 = ib * 64;
        if (tid < 64) xs[tid] = x2A[i0 + tid] + x2A[1536 + i0 + tid];
        __syncthreads();
        const void* W = z ? Wu : Wg;
        float* outp = (z ? uaccA : gaccA) + (ib & 1) * 6144;
        int j = jb * 512 + lane * 8;
        float acc[8] = {0,0,0,0,0,0,0,0};
        gemv_rows16<BF16>(W, 6144, xs + wave * 16, i0 + wave * 16, j, acc);
        block_reduce_512(acc, red, wave, lane);
        if (wave == 0) {
            #pragma unroll
            for (int q = 0; q < 8; ++q) atomicAdd(&outp[j + q], acc[q]);
        }
        __syncthreads();   // xs/red reused next vb
    }
    gbar(bar, 5 * NB);

    // ================= phase 5: down + GELU (288 vblocks: 3 jb x 96 ib, 64 rows)
    for (int vb = bid; vb < 288; vb += 256) {
        int jb = vb % 3, ib = vb / 3;
        int i0 = ib * 64;
        if (tid < 64) {
            int i = i0 + tid;
            float g = gaccA[i] + gaccA[6144 + i] + load1<BF16>(bg, i);
            float u = uaccA[i] + uaccA[6144 + i] + load1<BF16>(bu, i);
            float ge = 0.5f * g * (1.0f + erff(g * 0.70710678118654752f));
            xs[tid] = ge * u;
        }
        __syncthreads();
        int j = jb * 512 + lane * 8;
        float acc[8] = {0,0,0,0,0,0,0,0};
        gemv_rows16<BF16>(Wd, 1536, xs + wave * 16, i0 + wave * 16, j, acc);
        block_reduce_512(acc, red, wave, lane);
        if (wave == 0) {
            float* o = yacc + (ib & 3) * 1536;
            #pragma unroll
            for (int q = 0; q < 8; ++q) atomicAdd(&o[j + q], acc[q]);
        }
        __syncthreads();
    }
    gbar(bar, 6 * NB);

    // ================= phase 6: final ====
    if (bid == 0) {
        for (int j = tid; j < 1536; j += 256) {
            float b = load1<BF16>(bd, j);
            float v = x2A[j] + x2A[1536 + j]
                    + yacc[j] + yacc[1536 + j] + yacc[3072 + j] + yacc[4608 + j] + b;
            if constexpr (BF16) ((bf*)out)[j] = __float2bfloat16(v);
            else                ((float*)out)[j] = v;
        }
    }
}

__global__ __launch_bounds__(256, 2) void mega_kernel(
    const void* x, const void* kp, const void* vp,
    const void* Wq, const void* bq, const void* Wk, const void* bk,
    const void* Wv, const void* bv, const void* Wo, const void* bo,
    const void* Wg, const void* bg, const void* Wu, const void* bu,
    const void* Wd, const void* bd, void* out, float* ws, unsigned* bar) {
    __shared__ float xs[64];
    __shared__ float red[3 * 2048];
    __shared__ float wsum[8];
    __shared__ int pcnt;
    // dtype probe (per-block, no global round-trip)
    if (threadIdx.x == 0) pcnt = 0;
    __syncthreads();
    {
        const unsigned* xw = (const unsigned*)x;
        int ok = 0;
        for (int i = threadIdx.x; i < 768; i += 256) {
            unsigned e = (xw[i] >> 7) & 0xff;
            if (e >= 96 && e <= 142) ok++;
        }
        atomicAdd(&pcnt, ok);
    }
    // zero accumulators (72192 floats across 65536 threads)
    int idx = blockIdx.x * 256 + threadIdx.x;
    for (int k = idx; k < 72192; k += 65536) ws[k] = 0.f;
    __syncthreads();
    bool isbf = pcnt > 500;
    gbar(bar, NB);   // zeroing complete before any atomics
    if (isbf) mega_body<true >(x, kp, vp, Wq, bq, Wk, bk, Wv, bv, Wo, bo,
                               Wg, bg, Wu, bu, Wd, bd, out, ws, bar, xs, red, wsum);
    else      mega_body<false>(x, kp, vp, Wq, bq, Wk, bk, Wv, bv, Wo, bo,
                               Wg, bg, Wu, bu, Wd, bd, out, ws, bar, xs, red, wsum);
}

extern "C" void kernel_launch(void* const* d_in, const int* in_sizes, int n_in,
                              void* d_out, int out_size, void* d_ws, size_t ws_size,
                              hipStream_t stream) {
    const void* x  = d_in[0];
    const void* kp = d_in[1];
    const void* vp = d_in[2];
    const void* Wq = d_in[3];
    const void* bq = d_in[4];
    const void* Wk = d_in[5];
    const void* bk = d_in[6];
    const void* Wv = d_in[7];
    const void* bv = d_in[8];
    const void* Wo = d_in[9];
    const void* bo = d_in[10];
    const void* Wg = d_in[11];
    const void* bg = d_in[12];
    const void* Wu = d_in[13];
    const void* bu = d_in[14];
    const void* Wd = d_in[15];
    const void* bd = d_in[16];

    float* ws = (float*)d_ws;
    unsigned* bar = (unsigned*)(ws + 100000);   // outside kernel-zeroed region

    hipMemsetAsync(bar, 0, 64, stream);
    mega_kernel<<<256, 256, 0, stream>>>(x, kp, vp, Wq, bq, Wk, bk, Wv, bv,
                                         Wo, bo, Wg, bg, Wu, bu, Wd, bd,
                                         d_out, ws, bar);
}

// Round 7
// 260.019 us; speedup vs baseline: 1.5421x; 1.5421x over previous
//
#include <hip/hip_runtime.h>
#include <hip/hip_bf16.h>
#include <math.h>

#define PAST 8191
#define SCALEF 0.0625f  // 256^-0.5

using bf = __hip_bfloat16;

__device__ __forceinline__ float bf2f(unsigned short u) {
    return __uint_as_float(((unsigned)u) << 16);
}
__device__ __forceinline__ void unpack8(uint4 r, float* f) {
    f[0] = __uint_as_float(r.x << 16);
    f[1] = __uint_as_float(r.x & 0xffff0000u);
    f[2] = __uint_as_float(r.y << 16);
    f[3] = __uint_as_float(r.y & 0xffff0000u);
    f[4] = __uint_as_float(r.z << 16);
    f[5] = __uint_as_float(r.z & 0xffff0000u);
    f[6] = __uint_as_float(r.w << 16);
    f[7] = __uint_as_float(r.w & 0xffff0000u);
}

template<bool BF16>
__device__ __forceinline__ void load4(const void* P, size_t off, float* f) {
    if constexpr (BF16) {
        uint2 r = *reinterpret_cast<const uint2*>((const unsigned short*)P + off);
        f[0] = __uint_as_float(r.x << 16); f[1] = __uint_as_float(r.x & 0xffff0000u);
        f[2] = __uint_as_float(r.y << 16); f[3] = __uint_as_float(r.y & 0xffff0000u);
    } else {
        float4 a = *reinterpret_cast<const float4*>((const float*)P + off);
        f[0]=a.x; f[1]=a.y; f[2]=a.z; f[3]=a.w;
    }
}
template<bool BF16>
__device__ __forceinline__ float load1(const void* P, int i) {
    if constexpr (BF16) return bf2f(((const unsigned short*)P)[i]);
    else return ((const float*)P)[i];
}

// ---- dtype probe + workspace zeroing fused: grid 40 x 256 ----
__global__ __launch_bounds__(256) void probe_kernel(const unsigned int* __restrict__ xw,
                                                    float* __restrict__ zws,
                                                    int* __restrict__ flag) {
    int idx = blockIdx.x * 256 + threadIdx.x;
    for (int k = idx; k < 38400; k += 10240) zws[k] = 0.f;
    if (blockIdx.x == 0) {
        __shared__ int cnt;
        if (threadIdx.x == 0) cnt = 0;
        __syncthreads();
        int ok = 0;
        for (int i = threadIdx.x; i < 768; i += 256) {
            unsigned e = (xw[i] >> 7) & 0xff;
            if (e >= 96 && e <= 142) ok++;
        }
        atomicAdd(&cnt, ok);
        __syncthreads();
        if (threadIdx.x == 0) *flag = (cnt > 500) ? 1 : 0;
    }
}

// ---- GEMV core: 16 rows/wave, ALL loads staged in raw registers upfront ----
// Key change vs round 5: stage 16 uint4 (256 B/thread) with NO array reuse, so
// all 16 global_load_dwordx4 are simultaneously in flight (WAR-free); unpack+FMA
// consume them in order under counted vmcnt waits. fp32: 2x8 rows of float4[2]
// (same 256 B in flight per batch).
template<bool BF16>
__device__ __forceinline__ void gemv_rows16(const void* __restrict__ W, int ldw,
                                            const float* __restrict__ xs_wave,
                                            int row0, int j, float acc[8]) {
    if constexpr (BF16) {
        const unsigned short* Wp = (const unsigned short*)W;
        uint4 u0, u1, u2, u3, u4, u5, u6, u7, u8, u9, ua, ub, uc, ud, ue, uf;
        u0 = *reinterpret_cast<const uint4*>(Wp + (size_t)(row0 +  0) * ldw + j);
        u1 = *reinterpret_cast<const uint4*>(Wp + (size_t)(row0 +  1) * ldw + j);
        u2 = *reinterpret_cast<const uint4*>(Wp + (size_t)(row0 +  2) * ldw + j);
        u3 = *reinterpret_cast<const uint4*>(Wp + (size_t)(row0 +  3) * ldw + j);
        u4 = *reinterpret_cast<const uint4*>(Wp + (size_t)(row0 +  4) * ldw + j);
        u5 = *reinterpret_cast<const uint4*>(Wp + (size_t)(row0 +  5) * ldw + j);
        u6 = *reinterpret_cast<const uint4*>(Wp + (size_t)(row0 +  6) * ldw + j);
        u7 = *reinterpret_cast<const uint4*>(Wp + (size_t)(row0 +  7) * ldw + j);
        u8 = *reinterpret_cast<const uint4*>(Wp + (size_t)(row0 +  8) * ldw + j);
        u9 = *reinterpret_cast<const uint4*>(Wp + (size_t)(row0 +  9) * ldw + j);
        ua = *reinterpret_cast<const uint4*>(Wp + (size_t)(row0 + 10) * ldw + j);
        ub = *reinterpret_cast<const uint4*>(Wp + (size_t)(row0 + 11) * ldw + j);
        uc = *reinterpret_cast<const uint4*>(Wp + (size_t)(row0 + 12) * ldw + j);
        ud = *reinterpret_cast<const uint4*>(Wp + (size_t)(row0 + 13) * ldw + j);
        ue = *reinterpret_cast<const uint4*>(Wp + (size_t)(row0 + 14) * ldw + j);
        uf = *reinterpret_cast<const uint4*>(Wp + (size_t)(row0 + 15) * ldw + j);
        uint4 uu[16] = {u0,u1,u2,u3,u4,u5,u6,u7,u8,u9,ua,ub,uc,ud,ue,uf};
        #pragma unroll
        for (int r = 0; r < 16; ++r) {
            float f[8];
            unpack8(uu[r], f);
            float xv = xs_wave[r];
            #pragma unroll
            for (int q = 0; q < 8; ++q) acc[q] = fmaf(xv, f[q], acc[q]);
        }
    } else {
        const float* Wp = (const float*)W;
        #pragma unroll
        for (int i = 0; i < 16; i += 8) {
            float4 a0[8], a1[8];
            #pragma unroll
            for (int r = 0; r < 8; ++r) {
                const float* p = Wp + (size_t)(row0 + i + r) * ldw + j;
                a0[r] = *reinterpret_cast<const float4*>(p);
                a1[r] = *reinterpret_cast<const float4*>(p + 4);
            }
            #pragma unroll
            for (int r = 0; r < 8; ++r) {
                float xv = xs_wave[i + r];
                acc[0] = fmaf(xv, a0[r].x, acc[0]);
                acc[1] = fmaf(xv, a0[r].y, acc[1]);
                acc[2] = fmaf(xv, a0[r].z, acc[2]);
                acc[3] = fmaf(xv, a0[r].w, acc[3]);
                acc[4] = fmaf(xv, a1[r].x, acc[4]);
                acc[5] = fmaf(xv, a1[r].y, acc[5]);
                acc[6] = fmaf(xv, a1[r].z, acc[6]);
                acc[7] = fmaf(xv, a1[r].w, acc[7]);
            }
        }
    }
}

// ---- cross-wave reduction: waves 1-3 stage, wave 0 owns the final acc ----
__device__ __forceinline__ void block_reduce_512(float acc[8], float* red,
                                                 int wave, int lane) {
    if (wave > 0) {
        float* dst = red + (wave - 1) * 512 + lane * 8;
        #pragma unroll
        for (int q = 0; q < 8; ++q) dst[q] = acc[q];
    }
    __syncthreads();
    if (wave == 0) {
        int o = lane * 8;
        #pragma unroll
        for (int q = 0; q < 8; ++q)
            acc[q] += red[o + q] + red[512 + o + q] + red[1024 + o + q];
    }
}

// ---------------- QKV projection: grid (5, 24) x 256, 64-row blocks, x2-striped out ----
template<bool BF16>
__device__ void qkv_body(const void* __restrict__ x, const void* __restrict__ Wq,
                         const void* __restrict__ bq, const void* __restrict__ Wk,
                         const void* __restrict__ bk, const void* __restrict__ Wv,
                         const void* __restrict__ bv, float* __restrict__ qkv) {
    __shared__ float xs[64];
    __shared__ float red[3 * 512];
    int tid = threadIdx.x, wave = tid >> 6, lane = tid & 63;
    int i0 = blockIdx.y * 64;
    if (tid < 64) xs[tid] = load1<BF16>(x, i0 + tid);
    __syncthreads();
    int j = blockIdx.x * 512 + lane * 8;
    const void* W; const void* bias; int ldw, jl;
    if (j < 2048)      { W = Wq; bias = bq; ldw = 2048; jl = j; }
    else if (j < 2304) { W = Wk; bias = bk; ldw = 256;  jl = j - 2048; }
    else               { W = Wv; bias = bv; ldw = 256;  jl = j - 2304; }
    float acc[8] = {0,0,0,0,0,0,0,0};
    gemv_rows16<BF16>(W, ldw, xs + wave * 16, i0 + wave * 16, jl, acc);
    block_reduce_512(acc, red, wave, lane);
    if (wave == 0) {
        if (blockIdx.y == 0) {
            #pragma unroll
            for (int q = 0; q < 8; ++q) acc[q] += load1<BF16>(bias, jl + q);
        }
        float* out = qkv + (blockIdx.y & 1) * 2560;
        #pragma unroll
        for (int q = 0; q < 8; ++q) atomicAdd(&out[j + q], acc[q]);
    }
}
__global__ __launch_bounds__(256) void qkv_kernel(
    const void* x, const void* Wq, const void* bq, const void* Wk, const void* bk,
    const void* Wv, const void* bv, float* qkv, const int* flag) {
    if (*flag) qkv_body<true>(x, Wq, bq, Wk, bk, Wv, bv, qkv);
    else       qkv_body<false>(x, Wq, bq, Wk, bk, Wv, bv, qkv);
}

// ---------------- fused attention: grid 128 x 256 (64 pos/block, 16/wave) ----------
template<bool BF16>
__device__ void attn_body(const float* __restrict__ qkv, const void* __restrict__ k_past,
                          const void* __restrict__ v_past, float* __restrict__ attnout,
                          float* __restrict__ lpart) {
    __shared__ float wsum[8];
    __shared__ float red[3 * 2048];
    int tid = threadIdx.x, wave = tid >> 6, lane = tid & 63;
    if (tid < 8) wsum[tid] = 0.f;
    int d0 = lane * 4;
    const float* qkv1 = qkv + 2560;   // stripe 1
    float4 qreg[8];
    #pragma unroll
    for (int h = 0; h < 8; ++h) {
        float4 a = *reinterpret_cast<const float4*>(qkv + h * 256 + d0);
        float4 b = *reinterpret_cast<const float4*>(qkv1 + h * 256 + d0);
        qreg[h].x = a.x + b.x; qreg[h].y = a.y + b.y;
        qreg[h].z = a.z + b.z; qreg[h].w = a.w + b.w;
    }
    float4 ka = *reinterpret_cast<const float4*>(qkv + 2048 + d0);
    float4 kb = *reinterpret_cast<const float4*>(qkv1 + 2048 + d0);
    float4 va = *reinterpret_cast<const float4*>(qkv + 2304 + d0);
    float4 vb = *reinterpret_cast<const float4*>(qkv1 + 2304 + d0);
    float knew[4] = {ka.x+kb.x, ka.y+kb.y, ka.z+kb.z, ka.w+kb.w};
    float vnew[4] = {va.x+vb.x, va.y+vb.y, va.z+vb.z, va.w+vb.w};
    __syncthreads();

    float o[8][4];
    #pragma unroll
    for (int h = 0; h < 8; ++h)
        #pragma unroll
        for (int r = 0; r < 4; ++r) o[h][r] = 0.f;
    float wl[8] = {0,0,0,0,0,0,0,0};

    int p0 = blockIdx.x * 64 + wave * 16;
    for (int it = 0; it < 16; it += 8) {
        float kf[8][4], vf[8][4];
        if (p0 + it + 7 < PAST) {
            #pragma unroll
            for (int r = 0; r < 8; ++r)
                load4<BF16>(k_past, (size_t)(p0 + it + r) * 256 + d0, kf[r]);
            #pragma unroll
            for (int r = 0; r < 8; ++r)
                load4<BF16>(v_past, (size_t)(p0 + it + r) * 256 + d0, vf[r]);
        } else {
            #pragma unroll
            for (int r = 0; r < 8; ++r) {
                int p = p0 + it + r;
                if (p < PAST) {
                    load4<BF16>(k_past, (size_t)p * 256 + d0, kf[r]);
                    load4<BF16>(v_past, (size_t)p * 256 + d0, vf[r]);
                } else {
                    kf[r][0]=knew[0]; kf[r][1]=knew[1]; kf[r][2]=knew[2]; kf[r][3]=knew[3];
                    vf[r][0]=vnew[0]; vf[r][1]=vnew[1]; vf[r][2]=vnew[2]; vf[r][3]=vnew[3];
                }
            }
        }
        float part[8][8];
        #pragma unroll
        for (int r = 0; r < 8; ++r)
            #pragma unroll
            for (int h = 0; h < 8; ++h)
                part[r][h] = qreg[h].x*kf[r][0] + qreg[h].y*kf[r][1]
                           + qreg[h].z*kf[r][2] + qreg[h].w*kf[r][3];
        #pragma unroll
        for (int m = 1; m < 64; m <<= 1) {
            #pragma unroll
            for (int r = 0; r < 8; ++r)
                #pragma unroll
                for (int h = 0; h < 8; ++h)
                    part[r][h] += __shfl_xor(part[r][h], m, 64);
        }
        #pragma unroll
        for (int r = 0; r < 8; ++r)
            #pragma unroll
            for (int h = 0; h < 8; ++h) {
                float w = expf(part[r][h] * SCALEF);
                wl[h] += w;
                #pragma unroll
                for (int rr = 0; rr < 4; ++rr) o[h][rr] = fmaf(w, vf[r][rr], o[h][rr]);
            }
    }
    if (lane == 0) {
        #pragma unroll
        for (int h = 0; h < 8; ++h) atomicAdd(&wsum[h], wl[h]);
    }
    if (wave > 0) {
        float* dst = red + (wave - 1) * 2048;
        #pragma unroll
        for (int h = 0; h < 8; ++h)
            #pragma unroll
            for (int r = 0; r < 4; ++r) dst[h * 256 + d0 + r] = o[h][r];
    }
    __syncthreads();
    if (wave == 0) {
        #pragma unroll
        for (int h = 0; h < 8; ++h)
            #pragma unroll
            for (int r = 0; r < 4; ++r) {
                float v = o[h][r] + red[h*256 + d0 + r] + red[2048 + h*256 + d0 + r]
                        + red[4096 + h*256 + d0 + r];
                atomicAdd(&attnout[h * 256 + d0 + r], v);
            }
    }
    if (tid < 8) atomicAdd(&lpart[tid * 64 + (blockIdx.x & 63)], wsum[tid]);
}
__global__ __launch_bounds__(256) void attn_kernel(
    const float* qkv, const void* k_past, const void* v_past, float* attnout,
    float* lpart, const int* flag) {
    if (*flag) attn_body<true>(qkv, k_past, v_past, attnout, lpart);
    else       attn_body<false>(qkv, k_past, v_past, attnout, lpart);
}

// ---------------- O projection + residual: grid (3, 32) x 256, 64-row blocks ----
template<bool BF16>
__device__ void oproj_body(const float* __restrict__ attnout, const float* __restrict__ lpart,
                           const void* __restrict__ Wo, const void* __restrict__ bo,
                           const void* __restrict__ xin, float* __restrict__ x2) {
    __shared__ float xs[64];
    __shared__ float red[3 * 512];
    int tid = threadIdx.x, wave = tid >> 6, lane = tid & 63;
    int i0 = blockIdx.y * 64;
    int h = i0 >> 8;
    if (tid < 64) {
        float v = lpart[h * 64 + tid];
        #pragma unroll
        for (int m = 1; m < 64; m <<= 1) v += __shfl_xor(v, m, 64);
        xs[tid] = attnout[i0 + tid] * (1.0f / v);
    }
    __syncthreads();
    int j = blockIdx.x * 512 + lane * 8;
    float acc[8] = {0,0,0,0,0,0,0,0};
    gemv_rows16<BF16>(Wo, 1536, xs + wave * 16, i0 + wave * 16, j, acc);
    block_reduce_512(acc, red, wave, lane);
    if (wave == 0) {
        if (blockIdx.y == 0) {
            #pragma unroll
            for (int q = 0; q < 8; ++q)
                acc[q] += load1<BF16>(bo, j + q) + load1<BF16>(xin, j + q);
        }
        float* out = x2 + (blockIdx.y & 1) * 1536;
        #pragma unroll
        for (int q = 0; q < 8; ++q) atomicAdd(&out[j + q], acc[q]);
    }
}
__global__ __launch_bounds__(256) void oproj_kernel(
    const float* attnout, const float* lpart, const void* Wo, const void* bo,
    const void* xin, float* x2, const int* flag) {
    if (*flag) oproj_body<true>(attnout, lpart, Wo, bo, xin, x2);
    else       oproj_body<false>(attnout, lpart, Wo, bo, xin, x2);
}

// ---------------- gate/up GEMV: grid (12, 24, 2) x 256, 64-row blocks, striped out ----
template<bool BF16>
__device__ void gateup_body(const float* __restrict__ x2, const void* __restrict__ Wg,
                            const void* __restrict__ Wu, float* __restrict__ gacc,
                            float* __restrict__ uacc) {
    __shared__ float xs[64];
    __shared__ float red[3 * 512];
    int tid = threadIdx.x, wave = tid >> 6, lane = tid & 63;
    int i0 = blockIdx.y * 64;
    if (tid < 64) xs[tid] = x2[i0 + tid] + x2[1536 + i0 + tid];
    __syncthreads();
    const void* W = blockIdx.z ? Wu : Wg;
    float* out = (blockIdx.z ? uacc : gacc) + (blockIdx.y & 1) * 6144;
    int j = blockIdx.x * 512 + lane * 8;
    float acc[8] = {0,0,0,0,0,0,0,0};
    gemv_rows16<BF16>(W, 6144, xs + wave * 16, i0 + wave * 16, j, acc);
    block_reduce_512(acc, red, wave, lane);
    if (wave == 0) {
        #pragma unroll
        for (int q = 0; q < 8; ++q) atomicAdd(&out[j + q], acc[q]);
    }
}
__global__ __launch_bounds__(256) void gateup_kernel(
    const float* x2, const void* Wg, const void* Wu, float* gacc, float* uacc,
    const int* flag) {
    if (*flag) gateup_body<true>(x2, Wg, Wu, gacc, uacc);
    else       gateup_body<false>(x2, Wg, Wu, gacc, uacc);
}

// ---------------- down GEMV, fused GELU(g)*u: grid (3, 96) x 256, striped out ----
template<bool BF16>
__device__ void down_body(const float* __restrict__ gacc, const float* __restrict__ uacc,
                          const void* __restrict__ bg, const void* __restrict__ bu,
                          const void* __restrict__ Wd, float* __restrict__ yacc) {
    __shared__ float xs[64];
    __shared__ float red[3 * 512];
    int tid = threadIdx.x, wave = tid >> 6, lane = tid & 63;
    int i0 = blockIdx.y * 64;
    if (tid < 64) {
        int i = i0 + tid;
        float g = gacc[i] + gacc[6144 + i] + load1<BF16>(bg, i);
        float u = uacc[i] + uacc[6144 + i] + load1<BF16>(bu, i);
        float ge = 0.5f * g * (1.0f + erff(g * 0.70710678118654752f));
        xs[tid] = ge * u;
    }
    __syncthreads();
    int j = blockIdx.x * 512 + lane * 8;
    float acc[8] = {0,0,0,0,0,0,0,0};
    gemv_rows16<BF16>(Wd, 1536, xs + wave * 16, i0 + wave * 16, j, acc);
    block_reduce_512(acc, red, wave, lane);
    if (wave == 0) {
        float* out = yacc + (blockIdx.y & 1) * 1536;
        #pragma unroll
        for (int q = 0; q < 8; ++q) atomicAdd(&out[j + q], acc[q]);
    }
}
__global__ __launch_bounds__(256) void down_kernel(
    const float* gacc, const float* uacc, const void* bg, const void* bu,
    const void* Wd, float* yacc, const int* flag) {
    if (*flag) down_body<true>(gacc, uacc, bg, bu, Wd, yacc);
    else       down_body<false>(gacc, uacc, bg, bu, Wd, yacc);
}

// ---------------- final: out = (x2 + y + bd) in the input dtype ----------------
__global__ __launch_bounds__(256) void final_kernel(
    const float* __restrict__ x2, const float* __restrict__ yacc,
    const void* __restrict__ bd, void* __restrict__ out, const int* __restrict__ flag) {
    int j = blockIdx.x * 256 + threadIdx.x;
    if (j < 1536) {
        int isbf = *flag;
        float b = isbf ? bf2f(((const unsigned short*)bd)[j]) : ((const float*)bd)[j];
        float v = x2[j] + x2[1536 + j] + yacc[j] + yacc[1536 + j] + b;
        if (isbf) ((bf*)out)[j] = __float2bfloat16(v);
        else      ((float*)out)[j] = v;
    }
}

extern "C" void kernel_launch(void* const* d_in, const int* in_sizes, int n_in,
                              void* d_out, int out_size, void* d_ws, size_t ws_size,
                              hipStream_t stream) {
    const void* x  = d_in[0];
    const void* kp = d_in[1];
    const void* vp = d_in[2];
    const void* Wq = d_in[3];
    const void* bq = d_in[4];
    const void* Wk = d_in[5];
    const void* bk = d_in[6];
    const void* Wv = d_in[7];
    const void* bv = d_in[8];
    const void* Wo = d_in[9];
    const void* bo = d_in[10];
    const void* Wg = d_in[11];
    const void* bg = d_in[12];
    const void* Wu = d_in[13];
    const void* bu = d_in[14];
    const void* Wd = d_in[15];
    const void* bd = d_in[16];

    float* ws      = (float*)d_ws;
    float* qkv     = ws;             // 2 x 2560 = 5120
    float* x2      = ws + 5120;      // 2 x 1536 = 3072
    float* gacc    = ws + 8192;      // 2 x 6144 = 12288
    float* uacc    = ws + 20480;     // 2 x 6144 = 12288
    float* yacc    = ws + 32768;     // 2 x 1536 = 3072
    float* attnout = ws + 35840;     // 2048
    float* lpart   = ws + 37888;     // 512 = [8 heads][64 stripes]
    int*  flag     = (int*)(ws + 40960);

    // probe + zero ws[0:38400] in one dispatch
    probe_kernel<<<40, 256, 0, stream>>>((const unsigned int*)x, ws, flag);

    qkv_kernel<<<dim3(5, 24), 256, 0, stream>>>(x, Wq, bq, Wk, bk, Wv, bv, qkv, flag);
    attn_kernel<<<128, 256, 0, stream>>>(qkv, kp, vp, attnout, lpart, flag);
    oproj_kernel<<<dim3(3, 32), 256, 0, stream>>>(attnout, lpart, Wo, bo, x, x2, flag);
    gateup_kernel<<<dim3(12, 24, 2), 256, 0, stream>>>(x2, Wg, Wu, gacc, uacc, flag);
    down_kernel<<<dim3(3, 96), 256, 0, stream>>>(gacc, uacc, bg, bu, Wd, yacc, flag);
    final_kernel<<<6, 256, 0, stream>>>(x2, yacc, bd, d_out, flag);
}